// Round 17
// baseline (195.009 us; speedup 1.0000x reference)
//
#include <hip/hip_runtime.h>
#include <math.h>

// Shapes: B=3200, L=7, H=8, E=64, S=56, D=64, N=50
// queries [B,7,8,64], keys [B,56,8,64], values [B,56,8,64], mask [50,7,56]
// out [B,7,8,64] fp32.
//
// R11 + ROLLING V DMA RING (demand-duty-cycle experiment). Five designs
// plateau at 160-170 us = 5.1 TB/s real = 82% of the copy ceiling; delivered
// 8.4 B/cyc/CU vs 10.2 ceiling. Hypothesis: each wave is memory-silent
// during its ~2k-cycle compute tail and 4 waves/CU can't cover the gaps
// (R15's 8-wave test was invalid: its V loads re-rolled to serial register
// loads, VGPR=68). Here ALL traffic stays on batched global_load_lds with
// counted vmcnt, and V becomes a 3-buffer x 8-row LDS ring refilled from
// INSIDE PV (2 DMA ops per stage, 3 chunks always in flight), so demand
// persists through the tail. LDS 14336(K/P) + 6144(Vring) + 896(QL) =
// 21376 B -> 7 blocks/CU (vs R11's 4). Issue order: K DMA(14) -> Q(7) ->
// mask(7) -> V chunks 0-2 (6); vmcnt(13) = K+Q landed, m+V fly through
// scores; softmax's auto-wait retires m only (V newer); PV stages wait
// vmcnt(4/4/4/4/4/2/0). lgkmcnt(0) before each refill guards ds_read-
// before-DMA-overwrite. Scores lane=s (K fp32 b128 chunk-XOR bank-
// balanced x Q fp16 uniform bcast), shuffle softmax (no max-sub, scores
// bounded), P fp32 overlays dead K, deferred normalization.

typedef __attribute__((ext_vector_type(8))) _Float16 half8;

#define GLDS(gp, lp) __builtin_amdgcn_global_load_lds(                        \
    (const __attribute__((address_space(1))) void*)(gp),                      \
    (__attribute__((address_space(3))) void*)(lp), 16, 0, 0)

// PV stage: wait WAITN, consume 8-row CHUNK from VB[BUF], optionally refill
// chunk RC into VB[RB] (RC<0 = none). lgkmcnt(0) drains the vv reads before
// the refill DMA may overwrite the buffer.
#define PV_STAGE(BUF, CHUNK, WAITN, RC, RB)                                   \
    asm volatile("s_waitcnt vmcnt(" #WAITN ")" ::: "memory");                 \
    __builtin_amdgcn_sched_barrier(0);                                        \
    {                                                                         \
        float vv[8];                                                          \
        _Pragma("unroll")                                                     \
        for (int r = 0; r < 8; ++r) vv[r] = VB[BUF][r * 64 + lane];           \
        asm volatile("s_waitcnt lgkmcnt(0)" ::: "memory");                    \
        __builtin_amdgcn_sched_barrier(0);                                    \
        if ((RC) >= 0) {                                                      \
            _Pragma("unroll")                                                 \
            for (int j = 0; j < 2; ++j) {                                     \
                const int row = (RC) * 8 + j * 4 + rr;                        \
                GLDS(v + kbase + row * 512 + pp * 4,                          \
                     (char*)VB[RB] + j * 1024);                               \
            }                                                                 \
        }                                                                     \
        __builtin_amdgcn_sched_barrier(0);                                    \
        _Pragma("unroll")                                                     \
        for (int l = 0; l < 7; ++l) {                                         \
            const float4 p0 = *(const float4*)(&pbuf[l * 64 + (CHUNK) * 8]);  \
            const float4 p1 = *(const float4*)(&pbuf[l * 64 + (CHUNK) * 8 + 4]); \
            facc[l] = fmaf(p0.x, vv[0], facc[l]);                             \
            facc[l] = fmaf(p0.y, vv[1], facc[l]);                             \
            facc[l] = fmaf(p0.z, vv[2], facc[l]);                             \
            facc[l] = fmaf(p0.w, vv[3], facc[l]);                             \
            facc[l] = fmaf(p1.x, vv[4], facc[l]);                             \
            facc[l] = fmaf(p1.y, vv[5], facc[l]);                             \
            facc[l] = fmaf(p1.z, vv[6], facc[l]);                             \
            facc[l] = fmaf(p1.w, vv[7], facc[l]);                             \
        }                                                                     \
    }

__launch_bounds__(64, 4)
__global__ void fullattn_kernel(const float* __restrict__ q,
                                const float* __restrict__ k,
                                const float* __restrict__ v,
                                const float* __restrict__ mask,
                                float* __restrict__ out,
                                int nstations) {
    __shared__ __align__(16) float    KL[56 * 64];    // 14336 B; P overlays
    __shared__ __align__(16) float    VB[3][8 * 64];  // 6144 B rolling V ring
    __shared__ __align__(16) _Float16 QL[7 * 64];     // 896 B  (21376 total)

    const int lane = threadIdx.x;     // 0..63
    const int unit = blockIdx.x;
    const int b    = unit >> 3;
    const int h    = unit & 7;
    const int st   = b % nstations;

    const int kbase = b * 28672 + h * 64;  // keys/values
    const int qbase = b * 3584  + h * 64;  // queries/out

    const int rr = lane >> 4;   // DMA row-within-group
    const int pp = lane & 15;   // DMA slot

    // ---- group 1: K DMA (14 ops), chunk-XOR pre-swizzled source ----
    // DMA j fills floats [j*256,(j+1)*256): row = 4j+rr; slot pp holds
    // logical chunk c = pp ^ (row&15) -> score reads at (c ^ (s&15)) are
    // bank-balanced.
#pragma unroll
    for (int j = 0; j < 14; ++j) {
        const int row = j * 4 + rr;
        const int c   = pp ^ (row & 15);
        GLDS(k + kbase + row * 512 + c * 4, (char*)KL + j * 1024);
    }
    __builtin_amdgcn_sched_barrier(0);

    // ---- group 2: Q (7 ops, e = lane) ----
    float qr[7];
#pragma unroll
    for (int l = 0; l < 7; ++l) qr[l] = q[qbase + l * 512 + lane];
    __builtin_amdgcn_sched_barrier(0);

    // ---- group 3: mask (7 ops, pre-scaled) ----
    const int ml = (lane < 56) ? lane : 55;  // clamped s index
    float m[7];
#pragma unroll
    for (int l = 0; l < 7; ++l)
        m[l] = mask[st * 392 + l * 56 + ml] * 0.125f;  // scale = 1/sqrt(64)
    __builtin_amdgcn_sched_barrier(0);

    // ---- group 4: V chunks 0..2 (6 ops) -> ring buffers, rows 0..23 ----
#pragma unroll
    for (int c = 0; c < 3; ++c)
#pragma unroll
        for (int j = 0; j < 2; ++j) {
            const int row = c * 8 + j * 4 + rr;
            GLDS(v + kbase + row * 512 + pp * 4, (char*)VB[c] + j * 1024);
        }
    __builtin_amdgcn_sched_barrier(0);

    // ---- fence: K+Q landed (m 7 + V 6 = 13 newer stay in flight) ----
    asm volatile("s_waitcnt vmcnt(13)" ::: "memory");
    __builtin_amdgcn_sched_barrier(0);

    // ---- Q -> LDS fp16 ----
#pragma unroll
    for (int l = 0; l < 7; ++l) QL[l * 64 + lane] = (_Float16)qr[l];

    // ---- scores: lane = s, K fp32 b128 (XOR slots) x Q fp16 uniform ----
    const int x16 = ml & 15;
    float acc[7];
#pragma unroll
    for (int l = 0; l < 7; ++l) acc[l] = 0.0f;

#pragma unroll
    for (int c2 = 0; c2 < 8; ++c2) {
        const float4 kv0 = *(const float4*)(&KL[ml * 64 + (((2 * c2)     ^ x16) << 2)]);
        const float4 kv1 = *(const float4*)(&KL[ml * 64 + (((2 * c2 + 1) ^ x16) << 2)]);
#pragma unroll
        for (int l = 0; l < 7; ++l) {
            const half8 qv = *(const half8*)(&QL[l * 64 + c2 * 8]);  // uniform bcast
            acc[l] = fmaf(kv0.x, (float)qv[0], acc[l]);
            acc[l] = fmaf(kv0.y, (float)qv[1], acc[l]);
            acc[l] = fmaf(kv0.z, (float)qv[2], acc[l]);
            acc[l] = fmaf(kv0.w, (float)qv[3], acc[l]);
            acc[l] = fmaf(kv1.x, (float)qv[4], acc[l]);
            acc[l] = fmaf(kv1.y, (float)qv[5], acc[l]);
            acc[l] = fmaf(kv1.z, (float)qv[6], acc[l]);
            acc[l] = fmaf(kv1.w, (float)qv[7], acc[l]);
        }
    }

    // ---- softmax (no max-subtraction; scores bounded); P overlays K ----
    // compiler auto-waits the m loads here (vmcnt(6)); V ring stays in flight
    float* pbuf = KL;
    float rdenom[7];
#pragma unroll
    for (int l = 0; l < 7; ++l) {
        const float sc = acc[l] * m[l];
        const float p  = (lane < 56) ? __expf(sc) : 0.0f;
        float sum = p;
#pragma unroll
        for (int off = 32; off >= 1; off >>= 1)
            sum += __shfl_xor(sum, off);
        pbuf[l * 64 + lane] = p;
        rdenom[l] = __builtin_amdgcn_rcpf(sum);
    }

    // ---- PV: 7 stages x 8 rows; ring refilled from inside PV ----
    float facc[7];
#pragma unroll
    for (int l = 0; l < 7; ++l) facc[l] = 0.0f;

    PV_STAGE(0, 0, 4,  3, 0)   // wait V0 (V1,V2 out); refill rows 24-31 -> B0
    PV_STAGE(1, 1, 4,  4, 1)   // wait V1 (V2,V3 out); refill rows 32-39 -> B1
    PV_STAGE(2, 2, 4,  5, 2)   // wait V2 (V3,V4 out); refill rows 40-47 -> B2
    PV_STAGE(0, 3, 4,  6, 0)   // wait V3 (V4,V5 out); refill rows 48-55 -> B0
    PV_STAGE(1, 4, 4, -1, 0)   // wait V4 (V5,V6 out)
    PV_STAGE(2, 5, 2, -1, 0)   // wait V5 (V6 out)
    PV_STAGE(0, 6, 0, -1, 0)   // wait V6

    // ---- epilogue: deferred normalization + coalesced store ----
#pragma unroll
    for (int l = 0; l < 7; ++l)
        out[qbase + l * 512 + lane] = facc[l] * rdenom[l];
}

extern "C" void kernel_launch(void* const* d_in, const int* in_sizes, int n_in,
                              void* d_out, int out_size, void* d_ws, size_t ws_size,
                              hipStream_t stream) {
    const float* q    = (const float*)d_in[0];
    const float* k    = (const float*)d_in[1];
    const float* v    = (const float*)d_in[2];
    const float* mask = (const float*)d_in[3];
    float* out        = (float*)d_out;

    const int B = in_sizes[0] / (7 * 8 * 64);        // 3200
    const int nstations = in_sizes[3] / (7 * 56);    // 50

    fullattn_kernel<<<dim3(B * 8), dim3(64), 0, stream>>>(q, k, v, mask, out, nstations);
}